// Round 8
// baseline (420.510 us; speedup 1.0000x reference)
//
#include <hip/hip_runtime.h>

typedef __bf16 bf16x8 __attribute__((ext_vector_type(8)));
typedef __bf16 bf16x4 __attribute__((ext_vector_type(4)));
typedef float floatx4 __attribute__((ext_vector_type(4)));

#define GK 2048
#define S_LEN 2048
#define NH 16
#define DH 128
#define NKT (GK / 64)

__device__ __forceinline__ void gl2lds16c(const __bf16* g, char* l) {
    __builtin_amdgcn_global_load_lds(
        (const __attribute__((address_space(1))) void*)g,
        (__attribute__((address_space(3))) void*)l, 16, 0, 0);
}

// ---------------------------------------------------------------------------
// fp32 -> bf16 bulk convert (one float4 -> bf16x4 per thread)
// ---------------------------------------------------------------------------
__global__ __launch_bounds__(256) void cvt_bf16(const float* __restrict__ in,
                                                __bf16* __restrict__ out, int n4) {
    int i = blockIdx.x * 256 + threadIdx.x;
    if (i < n4) {
        const float4 v = ((const float4*)in)[i];
        bf16x4 h;
        h[0] = (__bf16)v.x; h[1] = (__bf16)v.y; h[2] = (__bf16)v.z; h[3] = (__bf16)v.w;
        ((bf16x4*)out)[i] = h;
    }
}

// concat-convert wq|wk|wv (each 2048x2048 fp32) -> one bf16 [6144][2048]
__global__ __launch_bounds__(256) void cvt3_bf16(const float* __restrict__ a,
                                                 const float* __restrict__ b,
                                                 const float* __restrict__ c,
                                                 __bf16* __restrict__ out) {
    const int per = 2048 * 2048 / 4;
    int i = blockIdx.x * 256 + threadIdx.x;      // 0 .. 3*per-1
    const float* src = a; int j = i;
    if (i >= 2 * per)      { src = c; j = i - 2 * per; }
    else if (i >= per)     { src = b; j = i - per; }
    const float4 v = ((const float4*)src)[j];
    bf16x4 h;
    h[0] = (__bf16)v.x; h[1] = (__bf16)v.y; h[2] = (__bf16)v.z; h[3] = (__bf16)v.w;
    ((bf16x4*)out)[i] = h;
}

// XCD-aware bijective remap of a linear block id (nwg must be %8==0).
__device__ __forceinline__ int xcd_remap(int L, int nwg) {
    return (L & 7) * (nwg >> 3) + (L >> 3);
}

// ---------------------------------------------------------------------------
// gemm_body5: 4-phase 256(M) x 192(N) tile, BK=64, 8 waves (2m x 4n),
// per-wave 128x48 out (acc[8][3], rows interleaved: phase q computes rows
// q*64 + wm*32 + {0,16}).  qkv grid: 16x32 = 512 blocks = 2 exact CU rounds.
// Idioms (all validated rounds 4-7):
//  - dead-region staging of tile t+2 into live buffer p=t&1:
//      A-slice q (rows q*64..q*64+63): entry/prefetch-read retires before
//      phase q MFMA -> dead after phase q barrier -> staged at phase q+1
//      (slice 3 at tile boundary). B (3 loads, regs from entry) dead after
//      phase 0 barrier -> staged phases 1-2.  7 loads/thread/tile.
//  - counted vmcnt(7) at tile entry; vmcnt(0) only on the peeled last tile;
//    raw s_barrier (no __syncthreads drain).
//  - T2 XOR swizzle, rule-21: linear gl2lds dest + pre-swizzled global
//    source + swizzled ds_read. elem(r,c) @ r*128 + (2c ^ ((r&7)<<4)).
//  - A-fragment ping-pong prefetch (phase q reads phase q+1's frags).
//  - T5 setprio around each 12-MFMA cluster.
// LDS: 2 x (A 256x64 = 32KB + B 192x64 = 24KB) = 112 KB.
// ---------------------------------------------------------------------------
__device__ __forceinline__ void gemm_body5(const __bf16* __restrict__ A,
                                           const __bf16* __restrict__ W,
                                           int m0, int n0, char* lds,
                                           floatx4 (*acc)[3]) {
    const int t = threadIdx.x, l = t & 63, wave = t >> 6;
    const int fr = l & 15, fq = l >> 4;
    const int wm = wave >> 2, wn = wave & 3;

    const int swcol = ((l & 7) * 8) ^ (((l >> 3) & 7) * 8);
    const __bf16* gA = A + (size_t)(m0 + wave * 8 + (l >> 3)) * GK + swcol;
    const __bf16* gW = W + (size_t)(n0 + wave * 8 + (l >> 3)) * GK + swcol;
    char* const ldsW = lds + wave * 1024;

    auto stageA = [&](int p, int kt, int q) {   // A rows q*64 .. q*64+63
        gl2lds16c(gA + (size_t)q * 64 * GK + kt * 64,
                  ldsW + p * 57344 + q * 8192);
    };
    auto stageBh = [&](int p, int kt, int h) {  // B rows h*64 .. h*64+63
        gl2lds16c(gW + (size_t)h * 64 * GK + kt * 64,
                  ldsW + p * 57344 + 32768 + h * 8192);
    };

    // prologue: tiles 0 and 1 fully staged (7 loads each)
#pragma unroll
    for (int q = 0; q < 4; q++) stageA(0, 0, q);
#pragma unroll
    for (int h = 0; h < 3; h++) stageBh(0, 0, h);
#pragma unroll
    for (int q = 0; q < 4; q++) stageA(1, 1, q);
#pragma unroll
    for (int h = 0; h < 3; h++) stageBh(1, 1, h);

    const int sw = (fr & 7) << 4;
    const int cb0 = (fq * 16) ^ sw;
    const int cb1 = (64 + fq * 16) ^ sw;

    for (int t0 = 0; t0 < NKT; t0++) {
        const int p = t0 & 1;
        if (t0 == NKT - 1) { asm volatile("s_waitcnt vmcnt(0)" ::: "memory"); }
        else               { asm volatile("s_waitcnt vmcnt(7)" ::: "memory"); }
        __builtin_amdgcn_s_barrier();
        asm volatile("" ::: "memory");

        const char* bufA = lds + p * 57344;
        const char* bufB = bufA + 32768;

        // exposed entry reads: B fragments (6) + phase-0 A fragments (4)
        bf16x8 bB[3][2];
#pragma unroll
        for (int j = 0; j < 3; j++) {
            const char* rb = bufB + (wn * 48 + j * 16 + fr) * 128;
            bB[j][0] = *(const bf16x8*)(rb + cb0);
            bB[j][1] = *(const bf16x8*)(rb + cb1);
        }
        bf16x8 af[2][2][2];          // [q&1][i][k-slot], static indices only
        {
            const char* ra = bufA + (wm * 32 + fr) * 128;
#pragma unroll
            for (int i = 0; i < 2; i++) {
                af[0][i][0] = *(const bf16x8*)(ra + i * 2048 + cb0);
                af[0][i][1] = *(const bf16x8*)(ra + i * 2048 + cb1);
            }
        }

#pragma unroll
        for (int q = 0; q < 4; q++) {
            if (t0 + 2 < NKT) {      // stage into regions certified dead
                if (q == 1) { stageA(p, t0 + 2, 0); stageBh(p, t0 + 2, 0); stageBh(p, t0 + 2, 1); }
                if (q == 2) { stageA(p, t0 + 2, 1); stageBh(p, t0 + 2, 2); }
                if (q == 3) { stageA(p, t0 + 2, 2); }
            }
            if (q < 3) {             // prefetch next phase's A frags (hidden under MFMA)
                const char* ra = bufA + ((q + 1) * 64 + wm * 32 + fr) * 128;
#pragma unroll
                for (int i = 0; i < 2; i++) {
                    af[(q + 1) & 1][i][0] = *(const bf16x8*)(ra + i * 2048 + cb0);
                    af[(q + 1) & 1][i][1] = *(const bf16x8*)(ra + i * 2048 + cb1);
                }
            }
            __builtin_amdgcn_s_setprio(1);
#pragma unroll
            for (int i = 0; i < 2; i++)
#pragma unroll
                for (int j = 0; j < 3; j++) {
                    acc[2 * q + i][j] = __builtin_amdgcn_mfma_f32_16x16x32_bf16(af[q & 1][i][0], bB[j][0], acc[2 * q + i][j], 0, 0, 0);
                    acc[2 * q + i][j] = __builtin_amdgcn_mfma_f32_16x16x32_bf16(af[q & 1][i][1], bB[j][1], acc[2 * q + i][j], 0, 0, 0);
                }
            __builtin_amdgcn_s_setprio(0);
            __builtin_amdgcn_s_barrier();
            asm volatile("" ::: "memory");
        }
        if (t0 + 2 < NKT) stageA(p, t0 + 2, 3);   // A slice 3 dead after ph3
    }
}

// ---------------------------------------------------------------------------
// gemm_body4: 4-phase 128(M) x 256(N) tile (round-7, validated) — used by
// gemm_out (256 blocks = 1 exact round).
// ---------------------------------------------------------------------------
__device__ __forceinline__ void gemm_body4(const __bf16* __restrict__ A,
                                           const __bf16* __restrict__ W,
                                           int m0, int n0, char* lds,
                                           floatx4 (*acc)[4]) {
    const int t = threadIdx.x, l = t & 63, wave = t >> 6;
    const int fr = l & 15, fq = l >> 4;
    const int wm = wave >> 2, wn = wave & 3;

    const int swcol = ((l & 7) * 8) ^ (((l >> 3) & 7) * 8);
    const __bf16* gA = A + (size_t)(m0 + wave * 8 + (l >> 3)) * GK + swcol;
    const __bf16* gW = W + (size_t)(n0 + wave * 8 + (l >> 3)) * GK + swcol;
    char* const ldsW = lds + wave * 1024;

    auto stageA = [&](int p, int kt, int c) {
        gl2lds16c(gA + (size_t)c * 64 * GK + kt * 64,
                  ldsW + p * 49152 + c * 8192);
    };
    auto stageBh = [&](int p, int kt, int h) {
        gl2lds16c(gW + (size_t)h * 64 * GK + kt * 64,
                  ldsW + p * 49152 + 16384 + h * 8192);
    };

    stageA(0, 0, 0); stageA(0, 0, 1);
#pragma unroll
    for (int h = 0; h < 4; h++) stageBh(0, 0, h);
    stageA(1, 1, 0); stageA(1, 1, 1);
#pragma unroll
    for (int h = 0; h < 4; h++) stageBh(1, 1, h);

    const int sw = (fr & 7) << 4;
    const int cb0 = (fq * 16) ^ sw;
    const int cb1 = (64 + fq * 16) ^ sw;

    for (int t0 = 0; t0 < NKT; t0++) {
        const int p = t0 & 1;
        if (t0 == NKT - 1) { asm volatile("s_waitcnt vmcnt(0)" ::: "memory"); }
        else               { asm volatile("s_waitcnt vmcnt(6)" ::: "memory"); }
        __builtin_amdgcn_s_barrier();
        asm volatile("" ::: "memory");

        const char* bufA = lds + p * 49152;
        const char* bufB = bufA + 16384;

        bf16x8 bB[4][2];
#pragma unroll
        for (int j = 0; j < 4; j++) {
            const char* rb = bufB + (wn * 64 + j * 16 + fr) * 128;
            bB[j][0] = *(const bf16x8*)(rb + cb0);
            bB[j][1] = *(const bf16x8*)(rb + cb1);
        }
        bf16x8 af[2][2];
        {
            const char* ra = bufA + (wm * 16 + fr) * 128;
            af[0][0] = *(const bf16x8*)(ra + cb0);
            af[0][1] = *(const bf16x8*)(ra + cb1);
        }

#pragma unroll
        for (int q = 0; q < 4; q++) {
            if (t0 + 2 < NKT) {
                if (q == 1) { stageBh(p, t0 + 2, 0); stageBh(p, t0 + 2, 1); }
                if (q == 2) { stageBh(p, t0 + 2, 2); stageBh(p, t0 + 2, 3); stageA(p, t0 + 2, 0); }
            }
            if (q < 3) {
                const char* ra = bufA + ((q + 1) * 32 + wm * 16 + fr) * 128;
                af[(q + 1) & 1][0] = *(const bf16x8*)(ra + cb0);
                af[(q + 1) & 1][1] = *(const bf16x8*)(ra + cb1);
            }
            __builtin_amdgcn_s_setprio(1);
#pragma unroll
            for (int j = 0; j < 4; j++) {
                acc[q][j] = __builtin_amdgcn_mfma_f32_16x16x32_bf16(af[q & 1][0], bB[j][0], acc[q][j], 0, 0, 0);
                acc[q][j] = __builtin_amdgcn_mfma_f32_16x16x32_bf16(af[q & 1][1], bB[j][1], acc[q][j], 0, 0, 0);
            }
            __builtin_amdgcn_s_setprio(0);
            __builtin_amdgcn_s_barrier();
            asm volatile("" ::: "memory");
        }
        if (t0 + 2 < NKT) stageA(p, t0 + 2, 1);
    }
}

// Fused QKV projection: A (4096x2048) x Wqkv (6144x2048). 512 blocks, 2 rounds.
// 192-wide tiles straddle q/k/v boundaries; per-fragment (wn,j) the 16-col
// span never crosses a 2048 multiple -> `which` is fragment-uniform.
__global__ __launch_bounds__(512, 2) void gemm_qkv(const __bf16* __restrict__ A,
                                                   const __bf16* __restrict__ W,
                                                   __bf16* __restrict__ qb,
                                                   __bf16* __restrict__ kb,
                                                   __bf16* __restrict__ vbT) {
    extern __shared__ __align__(16) char lds[];
    const int gx = gridDim.x;                         // 32 n-blocks
    const int L = blockIdx.x + gx * blockIdx.y;
    const int tid2 = xcd_remap(L, gx * (int)gridDim.y);
    const int m0 = (tid2 / gx) * 256, n0 = (tid2 % gx) * 192;
    floatx4 acc[8][3] = {};
    gemm_body5(A, W, m0, n0, lds, acc);

    const int lane = threadIdx.x & 63, wave = threadIdx.x >> 6;
    const int fr = lane & 15, fq = lane >> 4;
    const int wm = wave >> 2, wn = wave & 3;

    for (int mi = 0; mi < 8; mi++)
        for (int j = 0; j < 3; j++) {
            const int row = m0 + (mi >> 1) * 64 + wm * 32 + (mi & 1) * 16 + fq * 4;
            const int c0 = n0 + wn * 48 + j * 16;    // fragment base col
            const int which = c0 >> 11;              // 0=q 1=k 2=v, frag-uniform
            const int col = (c0 & 2047) + fr;
            if (which == 2) {
                // vbT[b][col][s]; b = row>>11, s = row&2047 (row%4==0 -> 8B aligned)
                __bf16* Cp = vbT + (((size_t)(row & ~2047)) << 11) +
                             (size_t)col * 2048 + (row & 2047);
                bf16x4 hv;
                for (int r = 0; r < 4; r++) hv[r] = (__bf16)acc[mi][j][r];
                *(bf16x4*)Cp = hv;
            } else {
                __bf16* dst = which ? kb : qb;
                for (int r = 0; r < 4; r++)
                    dst[(size_t)(row + r) * 2048 + col] = (__bf16)acc[mi][j][r];
            }
        }
}

// Out-projection: A (4096x2048) x Wo (2048x2048) -> fp32. 256 blocks, 1 round.
__global__ __launch_bounds__(512, 2) void gemm_out(const __bf16* __restrict__ A,
                                                   const __bf16* __restrict__ W,
                                                   float* __restrict__ C) {
    extern __shared__ __align__(16) char lds[];
    const int gx = gridDim.x;                         // 8
    const int L = blockIdx.x + gx * blockIdx.y;
    const int tid2 = xcd_remap(L, gx * (int)gridDim.y);
    const int m0 = (tid2 / gx) * 128, n0 = (tid2 % gx) * 256;
    floatx4 acc[4][4] = {};
    gemm_body4(A, W, m0, n0, lds, acc);

    const int lane = threadIdx.x & 63, wave = threadIdx.x >> 6;
    const int fr = lane & 15, fq = lane >> 4;
    const int wm = wave >> 2, wn = wave & 3;
    for (int mi = 0; mi < 4; mi++)
        for (int j = 0; j < 4; j++) {
            const int row = m0 + mi * 32 + wm * 16 + fq * 4;
            const int col = n0 + wn * 64 + j * 16 + fr;
            for (int r = 0; r < 4; r++)
                C[(size_t)(row + r) * 2048 + col] = acc[mi][j][r];
        }
}

// ---------------------------------------------------------------------------
// Fused RMSNorm (per head, DH=128, fp32 math) + RoPE, in-place on bf16 q/k.
// ---------------------------------------------------------------------------
__global__ __launch_bounds__(256) void rmsrope(__bf16* __restrict__ qb,
                                               __bf16* __restrict__ kb,
                                               const float* __restrict__ rope,
                                               const float* __restrict__ qw,
                                               const float* __restrict__ kw) {
    const int lane = threadIdx.x & 63;
    const int row = blockIdx.x * 4 + (threadIdx.x >> 6);   // (b*S + s)*H + h
    __bf16* p = (blockIdx.y ? kb : qb) + (size_t)row * DH;
    const float* w = blockIdx.y ? kw : qw;
    const int s = (row >> 4) & (S_LEN - 1);

    float t0 = (float)p[lane];
    float t1 = (float)p[lane + 64];
    float ss = t0 * t0 + t1 * t1;
    for (int o = 32; o; o >>= 1) ss += __shfl_xor(ss, o, 64);
    const float inv = rsqrtf(ss * (1.0f / 128.0f) + 1e-6f);
    t0 *= inv * w[lane];
    t1 *= inv * w[lane + 64];

    const float4 f = *(const float4*)(rope + (size_t)s * 256 + lane * 4);
    p[lane]      = (__bf16)(f.x * t0 + f.y * t1);
    p[lane + 64] = (__bf16)(f.z * t0 + f.w * t1);
}

// ---------------------------------------------------------------------------
// Flash attention v3 (round-5 version, frozen): KVBLK=64, double-buffered K/V
// via global_load_lds with counted vmcnt(8), T2 XOR-swizzled LDS (rule 21),
// fixed-max softmax, l-sum via all-ones register B-fragment MFMA.
// ---------------------------------------------------------------------------
__global__ __launch_bounds__(256, 2) void flash(const __bf16* __restrict__ Q,
                                                const __bf16* __restrict__ K,
                                                const __bf16* __restrict__ Vt_g,
                                                __bf16* __restrict__ O) {
    extern __shared__ __align__(16) char lds[];

    const int t = threadIdx.x, lane = t & 63, wave = t >> 6;
    const int fr = lane & 15, fq = lane >> 4;

    // T1 XCD remap: 16 q-blocks x 4 heads per XCD (K/V 4MB -> one L2)
    const int n = blockIdx.x + (int)gridDim.x * blockIdx.y;   // 0..511
    const int by = (n & 7) * 4 + (n >> 7);                    // b*16+h
    const int bx = (n >> 3) & 15;                             // q-block
    const int b = by >> 4, h = by & 15;

    const size_t baseQ = (size_t)b * S_LEN * 2048 + h * 128;
    const size_t baseV = (size_t)b * 2048 * 2048 + (size_t)h * 128 * 2048;
    const int q0 = bx * 128 + wave * 32;
    const float sc2 = 0.08838834764831845f * 1.4426950408889634f;  // (1/sqrt(128))*log2e
    const float M2 = 12.0f * 1.4426950408889634f;

    // Q fragments (regs, whole loop); fence so in-loop vmcnt counts only gl2lds
    bf16x8 qf[2][4];
#pragma unroll
    for (int i2 = 0; i2 < 2; i2++) {
        const __bf16* qp = Q + baseQ + (size_t)(q0 + i2 * 16 + fr) * 2048 + fq * 8;
#pragma unroll
        for (int c = 0; c < 4; c++) qf[i2][c] = *(const bf16x8*)(qp + c * 32);
    }
    asm volatile("s_waitcnt vmcnt(0)" ::: "memory");

    bf16x8 onesb;
#pragma unroll
    for (int e = 0; e < 8; e++) onesb[e] = (__bf16)1.0f;

    // staging geometry (pre-swizzled source columns)
    const int l4 = lane >> 4;            // K: row-in-4, chunk c16
    const int c16 = lane & 15;
    const int l3 = lane >> 3;            // V: row-in-8, chunk c8
    const int c8 = lane & 7;
    const __bf16* gK0 = K + baseQ + (size_t)(wave * 16 + l4) * 2048 + (c16 ^ l4) * 8;
    const __bf16* gK1 = K + baseQ + (size_t)(wave * 16 + l4) * 2048 + (c16 ^ (4 + l4)) * 8;
    const __bf16* gV  = Vt_g + baseV + (size_t)(wave * 8 + l3) * 2048 + (c8 ^ l3) * 8;

    char* const kdw = lds + wave * 4096;
    char* const vdw = lds + 32768 + wave * 1024;

    auto stage = [&](int p, int it2) {
        const size_t ko = (size_t)it2 * 64 * 2048;
        char* kd = kdw + p * 16384;
        gl2lds16c(gK0 + ko,                      kd);
        gl2lds16c(gK1 + ko + (size_t)4 * 2048,   kd + 1024);
        gl2lds16c(gK0 + ko + (size_t)8 * 2048,   kd + 2048);
        gl2lds16c(gK1 + ko + (size_t)12 * 2048,  kd + 3072);
        const __bf16* v = gV + it2 * 64;
        char* vd = vdw + p * 16384;
        gl2lds16c(v,                        vd);
        gl2lds16c(v + (size_t)32 * 2048,    vd + 4096);
        gl2lds16c(v + (size_t)64 * 2048,    vd + 8192);
        gl2lds16c(v + (size_t)96 * 2048,    vd + 12288);
    };

    stage(0, 0);
    stage(1, 1);

    floatx4 oa[2][9] = {};
    char* const Pw = lds + 65536 + wave * 4096;
    const int sw = (fr & 7) << 4;

    for (int it = 0; it < 32; ++it) {
        const int p = it & 1;
        if (it == 31) { asm volatile("s_waitcnt vmcnt(0)" ::: "memory"); }
        else          { asm volatile("s_waitcnt vmcnt(8)" ::: "memory"); }
        __builtin_amdgcn_s_barrier();
        asm volatile("" ::: "memory");

        const char* Kb = lds + p * 16384;
        const char* Vb = lds + 32768 + p * 16384;

        // ---- QK^T: sacc[i2][j] covers q-rows i2*16.., kv-cols j*16+fr ----
        floatx4 sacc[2][4] = {};
#pragma unroll
        for (int j = 0; j < 4; j++) {
            const char* kr = Kb + (j * 16 + fr) * 256;
            const bf16x8 kf0 = *(const bf16x8*)(kr + ((0 + fq * 16) ^ sw));
            const bf16x8 kf1 = *(const bf16x8*)(kr + ((64 + fq * 16) ^ sw));
            const bf16x8 kf2 = *(const bf16x8*)(kr + ((128 + fq * 16) ^ sw));
            const bf16x8 kf3 = *(const bf16x8*)(kr + ((192 + fq * 16) ^ sw));
            __builtin_amdgcn_s_setprio(1);
            sacc[0][j] = __builtin_amdgcn_mfma_f32_16x16x32_bf16(qf[0][0], kf0, sacc[0][j], 0, 0, 0);
            sacc[1][j] = __builtin_amdgcn_mfma_f32_16x16x32_bf16(qf[1][0], kf0, sacc[1][j], 0, 0, 0);
            sacc[0][j] = __builtin_amdgcn_mfma_f32_16x16x32_bf16(qf[0][1], kf1, sacc[0][j], 0, 0, 0);
            sacc[1][j] = __builtin_amdgcn_mfma_f32_16x16x32_bf16(qf[1][1], kf1, sacc[1][j], 0, 0, 0);
            sacc[0][j] = __builtin_amdgcn_mfma_f32_16x16x32_bf16(qf[0][2], kf2, sacc[0][j], 0, 0, 0);
            sacc[1][j] = __builtin_amdgcn_mfma_f32_16x16x32_bf16(qf[1][2], kf2, sacc[1][j], 0, 0, 0);
            sacc[0][j] = __builtin_amdgcn_mfma_f32_16x16x32_bf16(qf[0][3], kf3, sacc[0][j], 0, 0, 0);
            sacc[1][j] = __builtin_amdgcn_mfma_f32_16x16x32_bf16(qf[1][3], kf3, sacc[1][j], 0, 0, 0);
            __builtin_amdgcn_s_setprio(0);
        }

        // ---- softmax (fixed max) -> Ps (swizzled, per-wave) ----
#pragma unroll
        for (int i2 = 0; i2 < 2; i2++)
#pragma unroll
            for (int r = 0; r < 4; r++) {
                const int row = i2 * 16 + fq * 4 + r;
                char* pr = Pw + row * 128;
                const int rsw = ((fq * 4 + r) & 7) << 4;
#pragma unroll
                for (int j = 0; j < 4; j++)
                    *(__bf16*)(pr + ((j * 32 + fr * 2) ^ rsw)) =
                        (__bf16)exp2f(fmaf(sc2, sacc[i2][j][r], -M2));
            }

        // ---- PV: oa[i2][nb] over kv (kc=0,1) ----
        bf16x8 pf[2][2];
#pragma unroll
        for (int i2 = 0; i2 < 2; i2++) {
            const char* pr = Pw + (i2 * 16 + fr) * 128;
            pf[i2][0] = *(const bf16x8*)(pr + ((fq * 16) ^ sw));
            pf[i2][1] = *(const bf16x8*)(pr + ((64 + fq * 16) ^ sw));
        }
#pragma unroll
        for (int nb = 0; nb < 8; nb++) {
            const char* vr = Vb + (nb * 16 + fr) * 128;
            const bf16x8 vf0 = *(const bf16x8*)(vr + ((fq * 16) ^ sw));
            const bf16x8 vf1 = *(const bf16x8*)(vr + ((64 + fq * 16) ^ sw));
            __builtin_amdgcn_s_setprio(1);
            oa[0][nb] = __builtin_amdgcn_mfma_f32_16x16x32_bf16(pf[0][0], vf0, oa[0][nb], 0, 0, 0);
            oa[1][nb] = __builtin_amdgcn_mfma_f32_16x16x32_bf16(pf[1][0], vf0, oa[1][nb], 0, 0, 0);
            oa[0][nb] = __builtin_amdgcn_mfma_f32_16x16x32_bf16(pf[0][1], vf1, oa[0][nb], 0, 0, 0);
            oa[1][nb] = __builtin_amdgcn_mfma_f32_16x16x32_bf16(pf[1][1], vf1, oa[1][nb], 0, 0, 0);
            __builtin_amdgcn_s_setprio(0);
        }
        // l-sum: all-ones register B-fragment -> every col holds row-sum
        oa[0][8] = __builtin_amdgcn_mfma_f32_16x16x32_bf16(pf[0][0], onesb, oa[0][8], 0, 0, 0);
        oa[1][8] = __builtin_amdgcn_mfma_f32_16x16x32_bf16(pf[1][0], onesb, oa[1][8], 0, 0, 0);
        oa[0][8] = __builtin_amdgcn_mfma_f32_16x16x32_bf16(pf[0][1], onesb, oa[0][8], 0, 0, 0);
        oa[1][8] = __builtin_amdgcn_mfma_f32_16x16x32_bf16(pf[1][1], onesb, oa[1][8], 0, 0, 0);

        __builtin_amdgcn_s_barrier();      // all waves done reading buffer p
        asm volatile("" ::: "memory");
        if (it < 30) stage(p, it + 2);     // overwrite p for tile it+2
    }

    for (int i2 = 0; i2 < 2; i2++)
        for (int r = 0; r < 4; r++) {
            const float inv = 1.0f / oa[i2][8][r];
            __bf16* op = O + baseQ + (size_t)(q0 + i2 * 16 + fq * 4 + r) * 2048;
            for (int nb = 0; nb < 8; nb++)
                op[nb * 16 + fr] = (__bf16)(oa[i2][nb][r] * inv);
        }
}

// ---------------------------------------------------------------------------
extern "C" void kernel_launch(void* const* d_in, const int* in_sizes, int n_in,
                              void* d_out, int out_size, void* d_ws, size_t ws_size,
                              hipStream_t stream) {
    const float* x    = (const float*)d_in[0];
    const float* rope = (const float*)d_in[1];
    const float* wq   = (const float*)d_in[2];
    const float* wk   = (const float*)d_in[3];
    const float* wv   = (const float*)d_in[4];
    const float* wo   = (const float*)d_in[5];
    const float* qnw  = (const float*)d_in[6];
    const float* knw  = (const float*)d_in[7];
    float* out = (float*)d_out;

    static bool attr_set = false;
    if (!attr_set) {
        hipFuncSetAttribute((const void*)gemm_qkv,
                            hipFuncAttributeMaxDynamicSharedMemorySize, 114688);
        hipFuncSetAttribute((const void*)gemm_out,
                            hipFuncAttributeMaxDynamicSharedMemorySize, 98304);
        hipFuncSetAttribute((const void*)flash,
                            hipFuncAttributeMaxDynamicSharedMemorySize, 81920);
        attr_set = true;
    }

    const size_t NTOK = 2 * 2048;
    const size_t ELEMS = NTOK * 2048;            // 8388608
    __bf16* xb  = (__bf16*)d_ws;                 // 16 MB; reused as ob after flash
    __bf16* qb  = xb + ELEMS;                    // 16 MB; reused for wo_bf after flash
    __bf16* kb  = qb + ELEMS;
    __bf16* vbT = kb + ELEMS;
    __bf16* ob  = xb;
    // d_out (32 MB fp32) doubles as scratch for the concatenated bf16 QKV
    // weights (25.2 MB) — fully consumed by gemm_qkv before gemm_out writes it.
    __bf16* wqkv = (__bf16*)d_out;
    __bf16* wob  = qb;                           // wo bf16 (8 MB), written after flash

    cvt_bf16<<<(int)(ELEMS / 4) / 256, 256, 0, stream>>>(x, xb, (int)(ELEMS / 4));
    cvt3_bf16<<<3 * (2048 * 2048 / 4) / 256, 256, 0, stream>>>(wq, wk, wv, wqkv);
    gemm_qkv<<<dim3(6144 / 192, (unsigned)(NTOK / 256)), 512, 114688, stream>>>(xb, wqkv, qb, kb, vbT);
    rmsrope<<<dim3((unsigned)(NTOK * 16 / 4), 2), 256, 0, stream>>>(qb, kb, rope, qnw, knw);
    flash<<<dim3(S_LEN / 128, 2 * 16), 256, 81920, stream>>>(qb, kb, vbT, ob);
    cvt_bf16<<<(int)(2048 * 2048 / 4) / 256, 256, 0, stream>>>(wo, wob, 2048 * 2048 / 4);
    gemm_out<<<dim3(2048 / 256, (unsigned)(NTOK / 128)), 512, 98304, stream>>>(ob, wob, out);
}

// Round 9
// 382.269 us; speedup vs baseline: 1.1000x; 1.1000x over previous
//
#include <hip/hip_runtime.h>

typedef __bf16 bf16x8 __attribute__((ext_vector_type(8)));
typedef __bf16 bf16x4 __attribute__((ext_vector_type(4)));
typedef float floatx4 __attribute__((ext_vector_type(4)));
typedef unsigned int uintx4 __attribute__((ext_vector_type(4)));

#define GK 2048
#define S_LEN 2048
#define NH 16
#define DH 128
#define NKT (GK / 64)

__device__ __forceinline__ void gl2lds16c(const __bf16* g, char* l) {
    __builtin_amdgcn_global_load_lds(
        (const __attribute__((address_space(1))) void*)g,
        (__attribute__((address_space(3))) void*)l, 16, 0, 0);
}

// ---------------------------------------------------------------------------
// fp32 -> bf16 bulk convert (one float4 -> bf16x4 per thread)
// ---------------------------------------------------------------------------
__global__ __launch_bounds__(256) void cvt_bf16(const float* __restrict__ in,
                                                __bf16* __restrict__ out, int n4) {
    int i = blockIdx.x * 256 + threadIdx.x;
    if (i < n4) {
        const float4 v = ((const float4*)in)[i];
        bf16x4 h;
        h[0] = (__bf16)v.x; h[1] = (__bf16)v.y; h[2] = (__bf16)v.z; h[3] = (__bf16)v.w;
        ((bf16x4*)out)[i] = h;
    }
}

// concat-convert wq|wk|wv (each 2048x2048 fp32) -> one bf16 [6144][2048]
__global__ __launch_bounds__(256) void cvt3_bf16(const float* __restrict__ a,
                                                 const float* __restrict__ b,
                                                 const float* __restrict__ c,
                                                 __bf16* __restrict__ out) {
    const int per = 2048 * 2048 / 4;
    int i = blockIdx.x * 256 + threadIdx.x;      // 0 .. 3*per-1
    const float* src = a; int j = i;
    if (i >= 2 * per)      { src = c; j = i - 2 * per; }
    else if (i >= per)     { src = b; j = i - per; }
    const float4 v = ((const float4*)src)[j];
    bf16x4 h;
    h[0] = (__bf16)v.x; h[1] = (__bf16)v.y; h[2] = (__bf16)v.z; h[3] = (__bf16)v.w;
    ((bf16x4*)out)[i] = h;
}

// XCD-aware bijective remap of a linear block id (nwg must be %8==0).
__device__ __forceinline__ int xcd_remap(int L, int nwg) {
    return (L & 7) * (nwg >> 3) + (L >> 3);
}

// ---------------------------------------------------------------------------
// gemm_body5: 4-phase 256(M) x 192(N) tile (round-8, validated: 109 µs qkv,
// MfmaUtil 41%, 0 conflicts). See round-8 comments for the full derivation.
// ---------------------------------------------------------------------------
__device__ __forceinline__ void gemm_body5(const __bf16* __restrict__ A,
                                           const __bf16* __restrict__ W,
                                           int m0, int n0, char* lds,
                                           floatx4 (*acc)[3]) {
    const int t = threadIdx.x, l = t & 63, wave = t >> 6;
    const int fr = l & 15, fq = l >> 4;
    const int wm = wave >> 2, wn = wave & 3;

    const int swcol = ((l & 7) * 8) ^ (((l >> 3) & 7) * 8);
    const __bf16* gA = A + (size_t)(m0 + wave * 8 + (l >> 3)) * GK + swcol;
    const __bf16* gW = W + (size_t)(n0 + wave * 8 + (l >> 3)) * GK + swcol;
    char* const ldsW = lds + wave * 1024;

    auto stageA = [&](int p, int kt, int q) {   // A rows q*64 .. q*64+63
        gl2lds16c(gA + (size_t)q * 64 * GK + kt * 64,
                  ldsW + p * 57344 + q * 8192);
    };
    auto stageBh = [&](int p, int kt, int h) {  // B rows h*64 .. h*64+63
        gl2lds16c(gW + (size_t)h * 64 * GK + kt * 64,
                  ldsW + p * 57344 + 32768 + h * 8192);
    };

#pragma unroll
    for (int q = 0; q < 4; q++) stageA(0, 0, q);
#pragma unroll
    for (int h = 0; h < 3; h++) stageBh(0, 0, h);
#pragma unroll
    for (int q = 0; q < 4; q++) stageA(1, 1, q);
#pragma unroll
    for (int h = 0; h < 3; h++) stageBh(1, 1, h);

    const int sw = (fr & 7) << 4;
    const int cb0 = (fq * 16) ^ sw;
    const int cb1 = (64 + fq * 16) ^ sw;

    for (int t0 = 0; t0 < NKT; t0++) {
        const int p = t0 & 1;
        if (t0 == NKT - 1) { asm volatile("s_waitcnt vmcnt(0)" ::: "memory"); }
        else               { asm volatile("s_waitcnt vmcnt(7)" ::: "memory"); }
        __builtin_amdgcn_s_barrier();
        asm volatile("" ::: "memory");

        const char* bufA = lds + p * 57344;
        const char* bufB = bufA + 32768;

        bf16x8 bB[3][2];
#pragma unroll
        for (int j = 0; j < 3; j++) {
            const char* rb = bufB + (wn * 48 + j * 16 + fr) * 128;
            bB[j][0] = *(const bf16x8*)(rb + cb0);
            bB[j][1] = *(const bf16x8*)(rb + cb1);
        }
        bf16x8 af[2][2][2];          // [q&1][i][k-slot], static indices only
        {
            const char* ra = bufA + (wm * 32 + fr) * 128;
#pragma unroll
            for (int i = 0; i < 2; i++) {
                af[0][i][0] = *(const bf16x8*)(ra + i * 2048 + cb0);
                af[0][i][1] = *(const bf16x8*)(ra + i * 2048 + cb1);
            }
        }

#pragma unroll
        for (int q = 0; q < 4; q++) {
            if (t0 + 2 < NKT) {      // stage into regions certified dead
                if (q == 1) { stageA(p, t0 + 2, 0); stageBh(p, t0 + 2, 0); stageBh(p, t0 + 2, 1); }
                if (q == 2) { stageA(p, t0 + 2, 1); stageBh(p, t0 + 2, 2); }
                if (q == 3) { stageA(p, t0 + 2, 2); }
            }
            if (q < 3) {             // prefetch next phase's A frags (hidden under MFMA)
                const char* ra = bufA + ((q + 1) * 64 + wm * 32 + fr) * 128;
#pragma unroll
                for (int i = 0; i < 2; i++) {
                    af[(q + 1) & 1][i][0] = *(const bf16x8*)(ra + i * 2048 + cb0);
                    af[(q + 1) & 1][i][1] = *(const bf16x8*)(ra + i * 2048 + cb1);
                }
            }
            __builtin_amdgcn_s_setprio(1);
#pragma unroll
            for (int i = 0; i < 2; i++)
#pragma unroll
                for (int j = 0; j < 3; j++) {
                    acc[2 * q + i][j] = __builtin_amdgcn_mfma_f32_16x16x32_bf16(af[q & 1][i][0], bB[j][0], acc[2 * q + i][j], 0, 0, 0);
                    acc[2 * q + i][j] = __builtin_amdgcn_mfma_f32_16x16x32_bf16(af[q & 1][i][1], bB[j][1], acc[2 * q + i][j], 0, 0, 0);
                }
            __builtin_amdgcn_s_setprio(0);
            __builtin_amdgcn_s_barrier();
            asm volatile("" ::: "memory");
        }
        if (t0 + 2 < NKT) stageA(p, t0 + 2, 3);   // A slice 3 dead after ph3
    }
}

// ---------------------------------------------------------------------------
// gemm_body4: 4-phase 128(M) x 256(N) tile (round-7, validated) — gemm_out.
// ---------------------------------------------------------------------------
__device__ __forceinline__ void gemm_body4(const __bf16* __restrict__ A,
                                           const __bf16* __restrict__ W,
                                           int m0, int n0, char* lds,
                                           floatx4 (*acc)[4]) {
    const int t = threadIdx.x, l = t & 63, wave = t >> 6;
    const int fr = l & 15, fq = l >> 4;
    const int wm = wave >> 2, wn = wave & 3;

    const int swcol = ((l & 7) * 8) ^ (((l >> 3) & 7) * 8);
    const __bf16* gA = A + (size_t)(m0 + wave * 8 + (l >> 3)) * GK + swcol;
    const __bf16* gW = W + (size_t)(n0 + wave * 8 + (l >> 3)) * GK + swcol;
    char* const ldsW = lds + wave * 1024;

    auto stageA = [&](int p, int kt, int c) {
        gl2lds16c(gA + (size_t)c * 64 * GK + kt * 64,
                  ldsW + p * 49152 + c * 8192);
    };
    auto stageBh = [&](int p, int kt, int h) {
        gl2lds16c(gW + (size_t)h * 64 * GK + kt * 64,
                  ldsW + p * 49152 + 16384 + h * 8192);
    };

    stageA(0, 0, 0); stageA(0, 0, 1);
#pragma unroll
    for (int h = 0; h < 4; h++) stageBh(0, 0, h);
    stageA(1, 1, 0); stageA(1, 1, 1);
#pragma unroll
    for (int h = 0; h < 4; h++) stageBh(1, 1, h);

    const int sw = (fr & 7) << 4;
    const int cb0 = (fq * 16) ^ sw;
    const int cb1 = (64 + fq * 16) ^ sw;

    for (int t0 = 0; t0 < NKT; t0++) {
        const int p = t0 & 1;
        if (t0 == NKT - 1) { asm volatile("s_waitcnt vmcnt(0)" ::: "memory"); }
        else               { asm volatile("s_waitcnt vmcnt(6)" ::: "memory"); }
        __builtin_amdgcn_s_barrier();
        asm volatile("" ::: "memory");

        const char* bufA = lds + p * 49152;
        const char* bufB = bufA + 16384;

        bf16x8 bB[4][2];
#pragma unroll
        for (int j = 0; j < 4; j++) {
            const char* rb = bufB + (wn * 64 + j * 16 + fr) * 128;
            bB[j][0] = *(const bf16x8*)(rb + cb0);
            bB[j][1] = *(const bf16x8*)(rb + cb1);
        }
        bf16x8 af[2][2];
        {
            const char* ra = bufA + (wm * 16 + fr) * 128;
            af[0][0] = *(const bf16x8*)(ra + cb0);
            af[0][1] = *(const bf16x8*)(ra + cb1);
        }

#pragma unroll
        for (int q = 0; q < 4; q++) {
            if (t0 + 2 < NKT) {
                if (q == 1) { stageBh(p, t0 + 2, 0); stageBh(p, t0 + 2, 1); }
                if (q == 2) { stageBh(p, t0 + 2, 2); stageBh(p, t0 + 2, 3); stageA(p, t0 + 2, 0); }
            }
            if (q < 3) {
                const char* ra = bufA + ((q + 1) * 32 + wm * 16 + fr) * 128;
                af[(q + 1) & 1][0] = *(const bf16x8*)(ra + cb0);
                af[(q + 1) & 1][1] = *(const bf16x8*)(ra + cb1);
            }
            __builtin_amdgcn_s_setprio(1);
#pragma unroll
            for (int j = 0; j < 4; j++) {
                acc[q][j] = __builtin_amdgcn_mfma_f32_16x16x32_bf16(af[q & 1][0], bB[j][0], acc[q][j], 0, 0, 0);
                acc[q][j] = __builtin_amdgcn_mfma_f32_16x16x32_bf16(af[q & 1][1], bB[j][1], acc[q][j], 0, 0, 0);
            }
            __builtin_amdgcn_s_setprio(0);
            __builtin_amdgcn_s_barrier();
            asm volatile("" ::: "memory");
        }
        if (t0 + 2 < NKT) stageA(p, t0 + 2, 1);
    }
}

// Fused QKV projection: A (4096x2048) x Wqkv (6144x2048). 512 blocks, 2 rounds.
__global__ __launch_bounds__(512, 2) void gemm_qkv(const __bf16* __restrict__ A,
                                                   const __bf16* __restrict__ W,
                                                   __bf16* __restrict__ qb,
                                                   __bf16* __restrict__ kb,
                                                   __bf16* __restrict__ vbT) {
    extern __shared__ __align__(16) char lds[];
    const int gx = gridDim.x;                         // 32 n-blocks
    const int L = blockIdx.x + gx * blockIdx.y;
    const int tid2 = xcd_remap(L, gx * (int)gridDim.y);
    const int m0 = (tid2 / gx) * 256, n0 = (tid2 % gx) * 192;
    floatx4 acc[8][3] = {};
    gemm_body5(A, W, m0, n0, lds, acc);

    const int lane = threadIdx.x & 63, wave = threadIdx.x >> 6;
    const int fr = lane & 15, fq = lane >> 4;
    const int wm = wave >> 2, wn = wave & 3;

    for (int mi = 0; mi < 8; mi++)
        for (int j = 0; j < 3; j++) {
            const int row = m0 + (mi >> 1) * 64 + wm * 32 + (mi & 1) * 16 + fq * 4;
            const int c0 = n0 + wn * 48 + j * 16;    // fragment base col
            const int which = c0 >> 11;              // 0=q 1=k 2=v, frag-uniform
            const int col = (c0 & 2047) + fr;
            if (which == 2) {
                __bf16* Cp = vbT + (((size_t)(row & ~2047)) << 11) +
                             (size_t)col * 2048 + (row & 2047);
                bf16x4 hv;
                for (int r = 0; r < 4; r++) hv[r] = (__bf16)acc[mi][j][r];
                *(bf16x4*)Cp = hv;
            } else {
                __bf16* dst = which ? kb : qb;
                for (int r = 0; r < 4; r++)
                    dst[(size_t)(row + r) * 2048 + col] = (__bf16)acc[mi][j][r];
            }
        }
}

// Out-projection: A (4096x2048) x Wo (2048x2048) -> fp32. 256 blocks, 1 round.
__global__ __launch_bounds__(512, 2) void gemm_out(const __bf16* __restrict__ A,
                                                   const __bf16* __restrict__ W,
                                                   float* __restrict__ C) {
    extern __shared__ __align__(16) char lds[];
    const int gx = gridDim.x;                         // 8
    const int L = blockIdx.x + gx * blockIdx.y;
    const int tid2 = xcd_remap(L, gx * (int)gridDim.y);
    const int m0 = (tid2 / gx) * 128, n0 = (tid2 % gx) * 256;
    floatx4 acc[4][4] = {};
    gemm_body4(A, W, m0, n0, lds, acc);

    const int lane = threadIdx.x & 63, wave = threadIdx.x >> 6;
    const int fr = lane & 15, fq = lane >> 4;
    const int wm = wave >> 2, wn = wave & 3;
    for (int mi = 0; mi < 4; mi++)
        for (int j = 0; j < 4; j++) {
            const int row = m0 + mi * 32 + wm * 16 + fq * 4;
            const int col = n0 + wn * 64 + j * 16 + fr;
            for (int r = 0; r < 4; r++)
                C[(size_t)(row + r) * 2048 + col] = acc[mi][j][r];
        }
}

// ---------------------------------------------------------------------------
// Fused RMSNorm (per head, DH=128, fp32 math) + RoPE, in-place on bf16 q/k.
// ---------------------------------------------------------------------------
__global__ __launch_bounds__(256) void rmsrope(__bf16* __restrict__ qb,
                                               __bf16* __restrict__ kb,
                                               const float* __restrict__ rope,
                                               const float* __restrict__ qw,
                                               const float* __restrict__ kw) {
    const int lane = threadIdx.x & 63;
    const int row = blockIdx.x * 4 + (threadIdx.x >> 6);   // (b*S + s)*H + h
    __bf16* p = (blockIdx.y ? kb : qb) + (size_t)row * DH;
    const float* w = blockIdx.y ? kw : qw;
    const int s = (row >> 4) & (S_LEN - 1);

    float t0 = (float)p[lane];
    float t1 = (float)p[lane + 64];
    float ss = t0 * t0 + t1 * t1;
    for (int o = 32; o; o >>= 1) ss += __shfl_xor(ss, o, 64);
    const float inv = rsqrtf(ss * (1.0f / 128.0f) + 1e-6f);
    t0 *= inv * w[lane];
    t1 *= inv * w[lane + 64];

    const float4 f = *(const float4*)(rope + (size_t)s * 256 + lane * 4);
    p[lane]      = (__bf16)(f.x * t0 + f.y * t1);
    p[lane + 64] = (__bf16)(f.z * t0 + f.w * t1);
}

// ---------------------------------------------------------------------------
// Flash attention v4: swapped QK^T + fully in-register P (T12-style).
//   sacc[i2][j] = mfma(K_frag, Q_frag): lane (fr,fq) holds
//     S[q = i2*16+fr][kv = j*16 + fq*4 + r]  (q is now the MFMA column).
//   PV A-fragment needs P[q=fr][kv = kc*32 + fq*8 + e]; derivation:
//     e = 4h + r, source register j = 2kc + (fq>>1), source lane
//     FQ = 2*(fq&1) + h  (lane id = fr + 16*FQ).
//   Implementation: exp2 -> 16x v_cvt_pk_bf16_f32 (pack r-pairs) ->
//     32x ds_bpermute (pull words from L0 = fr+16*2*(fq&1), L1 = L0+16) ->
//     16x cndmask on (fq>>1) for the runtime-j parity (register indices stay
//     compile-time, rule 20). Replaces 32 cvt + 32 ds_write_b16 + 4
//     ds_read_b128 + ~100 VALU of swizzle address math; frees Ps (LDS 80->64K).
//   K/V staging (gl2lds, counted vmcnt(8)), barriers, l-sum ones-MFMA,
//   T1 remap, T5 setprio: unchanged from validated v3.
// ---------------------------------------------------------------------------
__global__ __launch_bounds__(256, 2) void flash(const __bf16* __restrict__ Q,
                                                const __bf16* __restrict__ K,
                                                const __bf16* __restrict__ Vt_g,
                                                __bf16* __restrict__ O) {
    extern __shared__ __align__(16) char lds[];

    const int t = threadIdx.x, lane = t & 63, wave = t >> 6;
    const int fr = lane & 15, fq = lane >> 4;

    // T1 XCD remap: 16 q-blocks x 4 heads per XCD (K/V 4MB -> one L2)
    const int n = blockIdx.x + (int)gridDim.x * blockIdx.y;   // 0..511
    const int by = (n & 7) * 4 + (n >> 7);                    // b*16+h
    const int bx = (n >> 3) & 15;                             // q-block
    const int b = by >> 4, h = by & 15;

    const size_t baseQ = (size_t)b * S_LEN * 2048 + h * 128;
    const size_t baseV = (size_t)b * 2048 * 2048 + (size_t)h * 128 * 2048;
    const int q0 = bx * 128 + wave * 32;
    const float sc2 = 0.08838834764831845f * 1.4426950408889634f;  // (1/sqrt(128))*log2e
    const float M2 = 12.0f * 1.4426950408889634f;

    // Q fragments (regs, whole loop); fence so in-loop vmcnt counts only gl2lds
    bf16x8 qf[2][4];
#pragma unroll
    for (int i2 = 0; i2 < 2; i2++) {
        const __bf16* qp = Q + baseQ + (size_t)(q0 + i2 * 16 + fr) * 2048 + fq * 8;
#pragma unroll
        for (int c = 0; c < 4; c++) qf[i2][c] = *(const bf16x8*)(qp + c * 32);
    }
    asm volatile("s_waitcnt vmcnt(0)" ::: "memory");

    bf16x8 onesb;
#pragma unroll
    for (int e = 0; e < 8; e++) onesb[e] = (__bf16)1.0f;

    // staging geometry (pre-swizzled source columns)
    const int l4 = lane >> 4;            // K: row-in-4, chunk c16
    const int c16 = lane & 15;
    const int l3 = lane >> 3;            // V: row-in-8, chunk c8
    const int c8 = lane & 7;
    const __bf16* gK0 = K + baseQ + (size_t)(wave * 16 + l4) * 2048 + (c16 ^ l4) * 8;
    const __bf16* gK1 = K + baseQ + (size_t)(wave * 16 + l4) * 2048 + (c16 ^ (4 + l4)) * 8;
    const __bf16* gV  = Vt_g + baseV + (size_t)(wave * 8 + l3) * 2048 + (c8 ^ l3) * 8;

    char* const kdw = lds + wave * 4096;
    char* const vdw = lds + 32768 + wave * 1024;

    auto stage = [&](int p, int it2) {
        const size_t ko = (size_t)it2 * 64 * 2048;
        char* kd = kdw + p * 16384;
        gl2lds16c(gK0 + ko,                      kd);
        gl2lds16c(gK1 + ko + (size_t)4 * 2048,   kd + 1024);
        gl2lds16c(gK0 + ko + (size_t)8 * 2048,   kd + 2048);
        gl2lds16c(gK1 + ko + (size_t)12 * 2048,  kd + 3072);
        const __bf16* v = gV + it2 * 64;
        char* vd = vdw + p * 16384;
        gl2lds16c(v,                        vd);
        gl2lds16c(v + (size_t)32 * 2048,    vd + 4096);
        gl2lds16c(v + (size_t)64 * 2048,    vd + 8192);
        gl2lds16c(v + (size_t)96 * 2048,    vd + 12288);
    };

    stage(0, 0);
    stage(1, 1);

    floatx4 oa[2][9] = {};
    const int sw = (fr & 7) << 4;
    // bpermute byte-indices for the P redistribution (hoisted, loop-invariant)
    const int il0 = (fr + 16 * (2 * (fq & 1))) * 4;   // h=0 source lane
    const int il1 = il0 + 64;                          // h=1 source lane (+16)
    const bool jhi = (fq >> 1) != 0;                   // runtime j-parity select

    for (int it = 0; it < 32; ++it) {
        const int p = it & 1;
        if (it == 31) { asm volatile("s_waitcnt vmcnt(0)" ::: "memory"); }
        else          { asm volatile("s_waitcnt vmcnt(8)" ::: "memory"); }
        __builtin_amdgcn_s_barrier();
        asm volatile("" ::: "memory");

        const char* Kb = lds + p * 16384;
        const char* Vb = lds + 32768 + p * 16384;

        // ---- swapped QK^T: sacc[i2][j] -> S[q=i2*16+fr][kv=j*16+fq*4+r] ----
        floatx4 sacc[2][4] = {};
#pragma unroll
        for (int j = 0; j < 4; j++) {
            const char* kr = Kb + (j * 16 + fr) * 256;
            const bf16x8 kf0 = *(const bf16x8*)(kr + ((0 + fq * 16) ^ sw));
            const bf16x8 kf1 = *(const bf16x8*)(kr + ((64 + fq * 16) ^ sw));
            const bf16x8 kf2 = *(const bf16x8*)(kr + ((128 + fq * 16) ^ sw));
            const bf16x8 kf3 = *(const bf16x8*)(kr + ((192 + fq * 16) ^ sw));
            __builtin_amdgcn_s_setprio(1);
            sacc[0][j] = __builtin_amdgcn_mfma_f32_16x16x32_bf16(kf0, qf[0][0], sacc[0][j], 0, 0, 0);
            sacc[1][j] = __builtin_amdgcn_mfma_f32_16x16x32_bf16(kf0, qf[1][0], sacc[1][j], 0, 0, 0);
            sacc[0][j] = __builtin_amdgcn_mfma_f32_16x16x32_bf16(kf1, qf[0][1], sacc[0][j], 0, 0, 0);
            sacc[1][j] = __builtin_amdgcn_mfma_f32_16x16x32_bf16(kf1, qf[1][1], sacc[1][j], 0, 0, 0);
            sacc[0][j] = __builtin_amdgcn_mfma_f32_16x16x32_bf16(kf2, qf[0][2], sacc[0][j], 0, 0, 0);
            sacc[1][j] = __builtin_amdgcn_mfma_f32_16x16x32_bf16(kf2, qf[1][2], sacc[1][j], 0, 0, 0);
            sacc[0][j] = __builtin_amdgcn_mfma_f32_16x16x32_bf16(kf3, qf[0][3], sacc[0][j], 0, 0, 0);
            sacc[1][j] = __builtin_amdgcn_mfma_f32_16x16x32_bf16(kf3, qf[1][3], sacc[1][j], 0, 0, 0);
            __builtin_amdgcn_s_setprio(0);
        }

        // ---- softmax (fixed max) + pack to bf16 pairs, all in-register ----
        unsigned int pk2[2][4][2];           // [i2][j][u]: (r=2u, r=2u+1)
#pragma unroll
        for (int i2 = 0; i2 < 2; i2++)
#pragma unroll
            for (int j = 0; j < 4; j++) {
                float pv[4];
#pragma unroll
                for (int r = 0; r < 4; r++)
                    pv[r] = exp2f(fmaf(sc2, sacc[i2][j][r], -M2));
                asm("v_cvt_pk_bf16_f32 %0, %1, %2"
                    : "=v"(pk2[i2][j][0]) : "v"(pv[0]), "v"(pv[1]));
                asm("v_cvt_pk_bf16_f32 %0, %1, %2"
                    : "=v"(pk2[i2][j][1]) : "v"(pv[2]), "v"(pv[3]));
            }

        // ---- redistribute P to PV A-fragment layout (bpermute + select) ----
        bf16x8 pf[2][2];
#pragma unroll
        for (int i2 = 0; i2 < 2; i2++)
#pragma unroll
            for (int kc = 0; kc < 2; kc++) {
                uintx4 w;
                const unsigned int a0 = __builtin_amdgcn_ds_bpermute(il0, pk2[i2][2 * kc][0]);
                const unsigned int b0 = __builtin_amdgcn_ds_bpermute(il0, pk2[i2][2 * kc + 1][0]);
                const unsigned int a1 = __builtin_amdgcn_ds_bpermute(il0, pk2[i2][2 * kc][1]);
                const unsigned int b1 = __builtin_amdgcn_ds_bpermute(il0, pk2[i2][2 * kc + 1][1]);
                const unsigned int a2 = __builtin_amdgcn_ds_bpermute(il1, pk2[i2][2 * kc][0]);
                const unsigned int b2 = __builtin_amdgcn_ds_bpermute(il1, pk2[i2][2 * kc + 1][0]);
                const unsigned int a3 = __builtin_amdgcn_ds_bpermute(il1, pk2[i2][2 * kc][1]);
                const unsigned int b3 = __builtin_amdgcn_ds_bpermute(il1, pk2[i2][2 * kc + 1][1]);
                w[0] = jhi ? b0 : a0;        // e=0,1  (h=0, u=0)
                w[1] = jhi ? b1 : a1;        // e=2,3  (h=0, u=1)
                w[2] = jhi ? b2 : a2;        // e=4,5  (h=1, u=0)
                w[3] = jhi ? b3 : a3;        // e=6,7  (h=1, u=1)
                pf[i2][kc] = *(const bf16x8*)&w;
            }

        // ---- PV: oa[i2][nb] over kv (kc=0,1) ----
#pragma unroll
        for (int nb = 0; nb < 8; nb++) {
            const char* vr = Vb + (nb * 16 + fr) * 128;
            const bf16x8 vf0 = *(const bf16x8*)(vr + ((fq * 16) ^ sw));
            const bf16x8 vf1 = *(const bf16x8*)(vr + ((64 + fq * 16) ^ sw));
            __builtin_amdgcn_s_setprio(1);
            oa[0][nb] = __builtin_amdgcn_mfma_f32_16x16x32_bf16(pf[0][0], vf0, oa[0][nb], 0, 0, 0);
            oa[1][nb] = __builtin_amdgcn_mfma_f32_16x16x32_bf16(pf[1][0], vf0, oa[1][nb], 0, 0, 0);
            oa[0][nb] = __builtin_amdgcn_mfma_f32_16x16x32_bf16(pf[0][1], vf1, oa[0][nb], 0, 0, 0);
            oa[1][nb] = __builtin_amdgcn_mfma_f32_16x16x32_bf16(pf[1][1], vf1, oa[1][nb], 0, 0, 0);
            __builtin_amdgcn_s_setprio(0);
        }
        // l-sum: all-ones register B-fragment -> every col holds row-sum
        oa[0][8] = __builtin_amdgcn_mfma_f32_16x16x32_bf16(pf[0][0], onesb, oa[0][8], 0, 0, 0);
        oa[1][8] = __builtin_amdgcn_mfma_f32_16x16x32_bf16(pf[1][0], onesb, oa[1][8], 0, 0, 0);
        oa[0][8] = __builtin_amdgcn_mfma_f32_16x16x32_bf16(pf[0][1], onesb, oa[0][8], 0, 0, 0);
        oa[1][8] = __builtin_amdgcn_mfma_f32_16x16x32_bf16(pf[1][1], onesb, oa[1][8], 0, 0, 0);

        __builtin_amdgcn_s_barrier();      // all waves done reading buffer p
        asm volatile("" ::: "memory");
        if (it < 30) stage(p, it + 2);     // overwrite p for tile it+2
    }

    for (int i2 = 0; i2 < 2; i2++)
        for (int r = 0; r < 4; r++) {
            const float inv = 1.0f / oa[i2][8][r];
            __bf16* op = O + baseQ + (size_t)(q0 + i2 * 16 + fq * 4 + r) * 2048;
            for (int nb = 0; nb < 8; nb++)
                op[nb * 16 + fr] = (__bf16)(oa[i2][nb][r] * inv);
        }
}

// ---------------------------------------------------------------------------
extern "C" void kernel_launch(void* const* d_in, const int* in_sizes, int n_in,
                              void* d_out, int out_size, void* d_ws, size_t ws_size,
                              hipStream_t stream) {
    const float* x    = (const float*)d_in[0];
    const float* rope = (const float*)d_in[1];
    const float* wq   = (const float*)d_in[2];
    const float* wk   = (const float*)d_in[3];
    const float* wv   = (const float*)d_in[4];
    const float* wo   = (const float*)d_in[5];
    const float* qnw  = (const float*)d_in[6];
    const float* knw  = (const float*)d_in[7];
    float* out = (float*)d_out;

    static bool attr_set = false;
    if (!attr_set) {
        hipFuncSetAttribute((const void*)gemm_qkv,
                            hipFuncAttributeMaxDynamicSharedMemorySize, 114688);
        hipFuncSetAttribute((const void*)gemm_out,
                            hipFuncAttributeMaxDynamicSharedMemorySize, 98304);
        hipFuncSetAttribute((const void*)flash,
                            hipFuncAttributeMaxDynamicSharedMemorySize, 65536);
        attr_set = true;
    }

    const size_t NTOK = 2 * 2048;
    const size_t ELEMS = NTOK * 2048;            // 8388608
    __bf16* xb  = (__bf16*)d_ws;                 // 16 MB; reused as ob after flash
    __bf16* qb  = xb + ELEMS;                    // 16 MB; reused for wo_bf after flash
    __bf16* kb  = qb + ELEMS;
    __bf16* vbT = kb + ELEMS;
    __bf16* ob  = xb;
    // d_out (32 MB fp32) doubles as scratch for the concatenated bf16 QKV
    // weights (25.2 MB) — fully consumed by gemm_qkv before gemm_out writes it.
    __bf16* wqkv = (__bf16*)d_out;
    __bf16* wob  = qb;                           // wo bf16 (8 MB), written after flash

    cvt_bf16<<<(int)(ELEMS / 4) / 256, 256, 0, stream>>>(x, xb, (int)(ELEMS / 4));
    cvt3_bf16<<<3 * (2048 * 2048 / 4) / 256, 256, 0, stream>>>(wq, wk, wv, wqkv);
    gemm_qkv<<<dim3(6144 / 192, (unsigned)(NTOK / 256)), 512, 114688, stream>>>(xb, wqkv, qb, kb, vbT);
    rmsrope<<<dim3((unsigned)(NTOK * 16 / 4), 2), 256, 0, stream>>>(qb, kb, rope, qnw, knw);
    flash<<<dim3(S_LEN / 128, 2 * 16), 256, 65536, stream>>>(qb, kb, vbT, ob);
    cvt_bf16<<<(int)(2048 * 2048 / 4) / 256, 256, 0, stream>>>(wo, wob, 2048 * 2048 / 4);
    gemm_out<<<dim3(2048 / 256, (unsigned)(NTOK / 128)), 512, 98304, stream>>>(ob, wob, out);
}